// Round 4
// baseline (569.747 us; speedup 1.0000x reference)
//
#include <hip/hip_runtime.h>
#include <hip/hip_bf16.h>
#include <math.h>

#define B_SZ 8192
#define D_SZ 1280
#define NE   4
#define NC   20
#define CD   64
#define NH   4
#define HD   16
#define FF   256

typedef __attribute__((ext_vector_type(8))) short bf16x8;
typedef __attribute__((ext_vector_type(4))) float f32x4;

__device__ inline unsigned int pk2(float lo, float hi) {
    union { __hip_bfloat16 h; unsigned short s; } a, b;
    a.h = __float2bfloat16(lo); b.h = __float2bfloat16(hi);
    return (unsigned int)a.s | ((unsigned int)b.s << 16);
}
__device__ inline __hip_bfloat16 us2bf(unsigned short u) {
    union { unsigned short s; __hip_bfloat16 h; } c; c.s = u; return c.h;
}

// ---------------- workspace layout (bytes) ----------------
// header: cnt[4]@0, pcnt[16]@16, offA[8]@80, poff[20]@112  (memset first 256 B)
#define WS_TOPI   256
#define WS_TOPW   (WS_TOPI + 2*B_SZ*4)
#define WS_IDX    (WS_TOPW + 2*B_SZ*4)
#define WS_WGT    (WS_IDX  + 2*B_SZ*4)
#define WS_ER0    (WS_WGT  + 2*B_SZ*4)
#define WS_ER1    (WS_ER0  + B_SZ*4)
#define WS_PRK    (WS_ER1  + B_SZ*4)
#define WS_BBE    (WS_PRK  + B_SZ*4)
#define WS_BBP    (WS_BBE  + 32*4*4)
#define WS_PRA    (WS_BBP  + 32*16*4)
#define WS_PRB    (WS_PRA  + (B_SZ+128)*4)
#define WS_PW1    (WS_PRB  + (B_SZ+128)*4)
#define WS_PW2    (WS_PW1  + (B_SZ+128)*4)
#define WS_PRW    (WS_PW2  + (B_SZ+128)*4)
#define WS_XSF    532480
#define XSF_ROWS  (2*B_SZ + 128)
#define WS_PWB    (WS_XSF + (size_t)XSF_ROWS * D_SZ * 2)
#define WS_IPWB   (WS_PWB  + (size_t)NE * D_SZ * D_SZ * 2)
#define WS_OPWB   (WS_IPWB + (size_t)NE * 192 * 64 * 2)
#define WS_FW1B   (WS_OPWB + (size_t)NE * 64 * 64 * 2)
#define WS_FW2B   (WS_FW1B + (size_t)NE * 256 * 64 * 2)

// ================= weight conversion =================
__global__ __launch_bounds__(256) void convert_pw(const float* __restrict__ pw,
                                                  __hip_bfloat16* __restrict__ pwb)
{
    size_t i = ((size_t)blockIdx.x * 256 + threadIdx.x) * 8;
    float4 a = *(const float4*)(pw + i);
    float4 b = *(const float4*)(pw + i + 4);
    __hip_bfloat16 h[8];
    h[0] = __float2bfloat16(a.x); h[1] = __float2bfloat16(a.y);
    h[2] = __float2bfloat16(a.z); h[3] = __float2bfloat16(a.w);
    h[4] = __float2bfloat16(b.x); h[5] = __float2bfloat16(b.y);
    h[6] = __float2bfloat16(b.z); h[7] = __float2bfloat16(b.w);
    *(uint4*)(pwb + i) = *(uint4*)h;
}

#define N_IPW (NE*192*64)
#define N_OPW (NE*64*64)
#define N_FW1 (NE*256*64)
#define N_FW2 (NE*64*256)
__global__ __launch_bounds__(256) void convert_small(
    const float* __restrict__ ipw, const float* __restrict__ opw,
    const float* __restrict__ fw1, const float* __restrict__ fw2,
    __hip_bfloat16* __restrict__ ipwb, __hip_bfloat16* __restrict__ opwb,
    __hip_bfloat16* __restrict__ fw1b, __hip_bfloat16* __restrict__ fw2b)
{
    size_t i = ((size_t)blockIdx.x * 256 + threadIdx.x) * 8;
    const float* src; __hip_bfloat16* dst; size_t off;
    if (i < N_IPW)                       { src = ipw; dst = ipwb; off = i; }
    else if (i < N_IPW + N_OPW)          { src = opw; dst = opwb; off = i - N_IPW; }
    else if (i < N_IPW + N_OPW + N_FW1)  { src = fw1; dst = fw1b; off = i - N_IPW - N_OPW; }
    else                                 { src = fw2; dst = fw2b; off = i - N_IPW - N_OPW - N_FW1; }
    float4 a = *(const float4*)(src + off);
    float4 b = *(const float4*)(src + off + 4);
    __hip_bfloat16 h[8];
    h[0] = __float2bfloat16(a.x); h[1] = __float2bfloat16(a.y);
    h[2] = __float2bfloat16(a.z); h[3] = __float2bfloat16(a.w);
    h[4] = __float2bfloat16(b.x); h[5] = __float2bfloat16(b.y);
    h[6] = __float2bfloat16(b.z); h[7] = __float2bfloat16(b.w);
    *(uint4*)(dst + off) = *(uint4*)h;
}

// ================= gate (no atomics) =================
__global__ __launch_bounds__(64) void gate_kernel(
    const float* __restrict__ x, const float* __restrict__ gw1, const float* __restrict__ gb1,
    const float* __restrict__ gw2, const float* __restrict__ gb2,
    int* __restrict__ topi, float* __restrict__ topw)
{
    const int b = blockIdx.x;
    const int lane = threadIdx.x;
    float acc[16];
#pragma unroll
    for (int j = 0; j < 16; ++j) acc[j] = 0.f;
    const float* xr = x + (size_t)b * D_SZ;
    for (int t = 0; t < NC; ++t) {
        float xv = xr[t * 64 + lane];
#pragma unroll
        for (int j = 0; j < 16; ++j) acc[j] += xv * gw1[j * D_SZ + t * 64 + lane];
    }
#pragma unroll
    for (int j = 0; j < 16; ++j) {
        acc[j] += __shfl_xor(acc[j], 32, 64);
        acc[j] += __shfl_xor(acc[j], 16, 64);
        acc[j] += __shfl_xor(acc[j], 8, 64);
        acc[j] += __shfl_xor(acc[j], 4, 64);
        acc[j] += __shfl_xor(acc[j], 2, 64);
        acc[j] += __shfl_xor(acc[j], 1, 64);
    }
    if (lane == 0) {
        float h[16];
#pragma unroll
        for (int j = 0; j < 16; ++j) h[j] = tanhf(acc[j] + gb1[j]);
        float l[4];
#pragma unroll
        for (int e = 0; e < 4; ++e) {
            float sv = gb2[e];
#pragma unroll
            for (int j = 0; j < 16; ++j) sv += h[j] * gw2[e * 16 + j];
            l[e] = sv;
        }
        float m = fmaxf(fmaxf(l[0], l[1]), fmaxf(l[2], l[3]));
        float p[4];
        float sum = 0.f;
#pragma unroll
        for (int e = 0; e < 4; ++e) { p[e] = expf(l[e] - m); sum += p[e]; }
#pragma unroll
        for (int e = 0; e < 4; ++e) p[e] /= sum;
        int i1 = 0;
#pragma unroll
        for (int e = 1; e < 4; ++e) if (p[e] > p[i1]) i1 = e;
        int i2 = (i1 == 0) ? 1 : 0;
#pragma unroll
        for (int e = 0; e < 4; ++e) if (e != i1 && p[e] > p[i2]) i2 = e;
        float s1 = p[i1], s2 = p[i2];
        float denom = s1 + s2 + 1e-6f;
        topi[b * 2 + 0] = i1;
        topi[b * 2 + 1] = i2;
        topw[b * 2 + 0] = s1 / denom;
        topw[b * 2 + 1] = s2 / denom;
    }
}

// ================= routing: block-aggregated count =================
__global__ __launch_bounds__(256) void count_kernel(
    const int* __restrict__ topi,
    int* __restrict__ cnt, int* __restrict__ pcnt,
    int* __restrict__ er0, int* __restrict__ er1, int* __restrict__ prk,
    int* __restrict__ bbe, int* __restrict__ bbp)
{
    __shared__ int he[4], hp[16];
    const int t = threadIdx.x;
    const int blk = blockIdx.x;
    const int b = blk * 256 + t;
    if (t < 4) he[t] = 0;
    if (t < 16) hp[t] = 0;
    __syncthreads();
    int e0 = topi[b * 2], e1 = topi[b * 2 + 1];
    er0[b] = atomicAdd(&he[e0], 1);
    er1[b] = atomicAdd(&he[e1], 1);
    prk[b] = atomicAdd(&hp[e0 * 4 + e1], 1);
    __syncthreads();
    if (t < 4)  bbe[blk * 4 + t]  = atomicAdd(&cnt[t], he[t]);
    if (t < 16) bbp[blk * 16 + t] = atomicAdd(&pcnt[t], hp[t]);
}

__global__ void offsets_kernel(const int* __restrict__ cnt, const int* __restrict__ pcnt,
                               int* __restrict__ offA, int* __restrict__ poff,
                               float* __restrict__ load_out)
{
    if (threadIdx.x == 0 && blockIdx.x == 0) {
        int a = 0;
#pragma unroll
        for (int e = 0; e < 4; ++e) { offA[e] = a; a += cnt[e]; }
        offA[4] = a;
        int q = 0;
#pragma unroll
        for (int p = 0; p < 16; ++p) { poff[p] = q; q += pcnt[p]; }
        poff[16] = q;
#pragma unroll
        for (int e = 0; e < 4; ++e) load_out[e] = (float)cnt[e];
    }
}

__global__ __launch_bounds__(256) void fill_kernel(
    const int* __restrict__ topi, const float* __restrict__ topw,
    const int* __restrict__ offA, const int* __restrict__ poff,
    const int* __restrict__ er0, const int* __restrict__ er1, const int* __restrict__ prk,
    const int* __restrict__ bbe, const int* __restrict__ bbp,
    int* __restrict__ idx_list, float* __restrict__ wgt_list,
    int* __restrict__ prA, int* __restrict__ prB,
    float* __restrict__ pw1, float* __restrict__ pw2, int* __restrict__ prow)
{
    const int b = blockIdx.x * 256 + threadIdx.x;
    const int blk = blockIdx.x;
    int e0 = topi[b * 2], e1 = topi[b * 2 + 1];
    float w0 = topw[b * 2], w1 = topw[b * 2 + 1];
    int slot0 = offA[e0] + bbe[blk * 4 + e0] + er0[b];
    int slot1 = offA[e1] + bbe[blk * 4 + e1] + er1[b];
    idx_list[slot0] = b; wgt_list[slot0] = w0;
    idx_list[slot1] = b; wgt_list[slot1] = w1;
    int p = e0 * 4 + e1;
    int pos = poff[p] + bbp[blk * 16 + p] + prk[b];
    prA[pos] = slot0; prB[pos] = slot1;
    pw1[pos] = w0; pw2[pos] = w1; prow[pos] = b;
}

// ================= expert inner — wave-per-token, single LDS buffer ========
// v4: LDS 33792 -> 18432 B (big[32][72] only): mid eliminated (Q|K and P
// time-share big cols 0..31; xn lives in af registers), vt eliminated (V's
// MFMA B-fragment built in-register via 8 ds_bpermute + selects), per-head O
// kept in registers (packed bf16). No asm fences / sched_barriers: all DS ops
// are compiler-visible (same array -> may-alias -> order kept) and a wave's
// LDS ops complete in-order on the DS pipe. Stage-8 store is vectorized via
// an LDS roundtrip so HBM lines are written whole (kills write amplification).
// __launch_bounds__(256,5): VGPR cap 102 (no spill), 5 blocks/CU = 20 waves.
__global__ __launch_bounds__(256, 5) void expert_inner(
    const float* __restrict__ x, const float* __restrict__ pos,
    const float* __restrict__ n1g,
    const __hip_bfloat16* __restrict__ ipwb, const float* __restrict__ ipb,
    const __hip_bfloat16* __restrict__ opwb, const float* __restrict__ opb,
    const float* __restrict__ ls1, const float* __restrict__ n2g,
    const __hip_bfloat16* __restrict__ fw1b, const float* __restrict__ fb1,
    const __hip_bfloat16* __restrict__ fw2b, const float* __restrict__ fb2,
    const float* __restrict__ ls2,
    const int* __restrict__ offA, const int* __restrict__ idx_list,
    const float* __restrict__ wgt_list,
    __hip_bfloat16* __restrict__ xsf)
{
    // stride 72 elem = 144 B = 36 dw -> column reads are 2-way bank (free),
    // rows 16B-aligned for b128.
    __shared__ __hip_bfloat16 s_big[4][32][72];   // 4*4608 = 18432 B

    const int t = threadIdx.x;
    const int w = t >> 6;
    const int lane = t & 63;
    const int l15 = lane & 15, lg = lane >> 4;
    const int s = blockIdx.x * 4 + w;
    const int e = (s >= offA[1]) + (s >= offA[2]) + (s >= offA[3]);
    const int b = idx_list[s];
    const float wgt = wgt_list[s];

    __hip_bfloat16 (* const big)[72] = s_big[w];

    const float* xg = x + (size_t)b * D_SZ;
    const float* pg = pos + (size_t)e * D_SZ;
    const __hip_bfloat16* ipw_e = ipwb + (size_t)e * 192 * 64;
    const float* ipb_e = ipb + e * 192;

    f32x4 xsr[2][4];   // residual, C-layout (row = mt*16+lg*4+r, col = nt*16+l15)

    // ---- stage 1: load x+pos, rmsnorm1 -> big (rows 20..31 exact zeros) ----
#pragma unroll
    for (int mt = 0; mt < 2; ++mt)
#pragma unroll
        for (int r = 0; r < 4; ++r) {
            const int row = mt * 16 + lg * 4 + r;
#pragma unroll
            for (int nt = 0; nt < 4; ++nt) {
                float v = 0.f;
                if (row < NC) v = xg[row * 64 + nt * 16 + l15] + pg[row * 64 + nt * 16 + l15];
                xsr[mt][nt][r] = v;
            }
        }
    {
        float g1[4];
#pragma unroll
        for (int nt = 0; nt < 4; ++nt) g1[nt] = n1g[e * CD + nt * 16 + l15];
#pragma unroll
        for (int mt = 0; mt < 2; ++mt)
#pragma unroll
            for (int r = 0; r < 4; ++r) {
                const int row = mt * 16 + lg * 4 + r;
                float ss = 0.f;
#pragma unroll
                for (int nt = 0; nt < 4; ++nt) ss += xsr[mt][nt][r] * xsr[mt][nt][r];
                ss += __shfl_xor(ss, 1); ss += __shfl_xor(ss, 2);
                ss += __shfl_xor(ss, 4); ss += __shfl_xor(ss, 8);
                float inv = __builtin_amdgcn_rcpf(sqrtf(ss) * 0.125f + 1e-8f);
#pragma unroll
                for (int nt = 0; nt < 4; ++nt)
                    big[row][nt * 16 + l15] = __float2bfloat16(xsr[mt][nt][r] * inv * g1[nt]);
            }
    }

    // A-fragments of normed x (register-resident for the whole attention)
    bf16x8 af[2][2];
#pragma unroll
    for (int mt = 0; mt < 2; ++mt)
#pragma unroll
        for (int ks = 0; ks < 2; ++ks)
            af[mt][ks] = *(const bf16x8*)&big[mt * 16 + l15][ks * 32 + lg * 8];

    // ---- stages 2+3: per-head qkv -> attention; O packed in registers ----
    unsigned int opk[NH][4];
#pragma unroll
    for (int h = 0; h < NH; ++h) {
        const int nq = h * 16 + l15;
        f32x4 qa[2], ka[2], va[2];
#pragma unroll
        for (int mt = 0; mt < 2; ++mt) { qa[mt] = (f32x4){0,0,0,0}; ka[mt] = (f32x4){0,0,0,0}; va[mt] = (f32x4){0,0,0,0}; }
#pragma unroll
        for (int ks = 0; ks < 2; ++ks) {
            bf16x8 wq = *(const bf16x8*)(ipw_e + (size_t)(nq) * 64 + ks * 32 + lg * 8);
            bf16x8 wk = *(const bf16x8*)(ipw_e + (size_t)(64 + nq) * 64 + ks * 32 + lg * 8);
            bf16x8 wv = *(const bf16x8*)(ipw_e + (size_t)(128 + nq) * 64 + ks * 32 + lg * 8);
#pragma unroll
            for (int mt = 0; mt < 2; ++mt) {
                qa[mt] = __builtin_amdgcn_mfma_f32_16x16x32_bf16(af[mt][ks], wq, qa[mt], 0, 0, 0);
                ka[mt] = __builtin_amdgcn_mfma_f32_16x16x32_bf16(af[mt][ks], wk, ka[mt], 0, 0, 0);
                va[mt] = __builtin_amdgcn_mfma_f32_16x16x32_bf16(af[mt][ks], wv, va[mt], 0, 0, 0);
            }
        }
        const float biq = ipb_e[nq], bik = ipb_e[64 + nq], biv = ipb_e[128 + nq];

        // --- V B-fragment via lane permutation (no LDS) ---
        // lane (l15,lg) needs V[k=lg*8+j][d=l15]; source pairs live in lanes
        // (2*(lg&1))*16+l15 (j0..3) and +16 (j4..7); mt half chosen by lg>=2.
        unsigned int vp0[2], vp1[2];
#pragma unroll
        for (int mt = 0; mt < 2; ++mt) {
            vp0[mt] = pk2(va[mt][0] + biv, va[mt][1] + biv);
            vp1[mt] = pk2(va[mt][2] + biv, va[mt][3] + biv);
        }
        const int aA = (((lg & 1) * 32) + l15) * 4;
        const int aB = aA + 64;
        int d0a = __builtin_amdgcn_ds_bpermute(aA, (int)vp0[0]);
        int d0b = __builtin_amdgcn_ds_bpermute(aA, (int)vp0[1]);
        int d1a = __builtin_amdgcn_ds_bpermute(aA, (int)vp1[0]);
        int d1b = __builtin_amdgcn_ds_bpermute(aA, (int)vp1[1]);
        int d2a = __builtin_amdgcn_ds_bpermute(aB, (int)vp0[0]);
        int d2b = __builtin_amdgcn_ds_bpermute(aB, (int)vp0[1]);
        int d3a = __builtin_amdgcn_ds_bpermute(aB, (int)vp1[0]);
        int d3b = __builtin_amdgcn_ds_bpermute(aB, (int)vp1[1]);
        const bool hi2 = (lg >= 2);
        union { int i[4]; bf16x8 v; } uv;
        uv.i[0] = hi2 ? d0b : d0a;
        uv.i[1] = hi2 ? d1b : d1a;
        uv.i[2] = hi2 ? d2b : d2a;
        uv.i[3] = hi2 ? d3b : d3a;
        const bf16x8 bv = uv.v;

        // --- Q|K transpose through big cols 0..31 ---
#pragma unroll
        for (int mt = 0; mt < 2; ++mt)
#pragma unroll
            for (int r = 0; r < 4; ++r) {
                const int row = mt * 16 + lg * 4 + r;
                big[row][l15]      = __float2bfloat16(qa[mt][r] + biq);
                big[row][16 + l15] = __float2bfloat16(ka[mt][r] + bik);
            }

        bf16x8 aq[2], bk[2];
        const bf16x8 zf = {0,0,0,0,0,0,0,0};
#pragma unroll
        for (int mt = 0; mt < 2; ++mt) {
            aq[mt] = zf;
            if (lg < 2) aq[mt] = *(const bf16x8*)&big[mt * 16 + l15][lg * 8];
        }
#pragma unroll
        for (int nt = 0; nt < 2; ++nt) {
            bk[nt] = zf;
            if (lg < 2) bk[nt] = *(const bf16x8*)&big[nt * 16 + l15][16 + lg * 8];
        }

        f32x4 sc[2][2];
#pragma unroll
        for (int mt = 0; mt < 2; ++mt)
#pragma unroll
            for (int nt = 0; nt < 2; ++nt)
                sc[mt][nt] = __builtin_amdgcn_mfma_f32_16x16x32_bf16(aq[mt], bk[nt], (f32x4){0,0,0,0}, 0, 0, 0);

        // softmax (no max-subtract: |S|*0.25 tiny with 0.02-scale weights);
        // keys 20..31 excluded via l15<4 mask; P overwrites big cols 0..31.
#pragma unroll
        for (int mt = 0; mt < 2; ++mt)
#pragma unroll
            for (int r = 0; r < 4; ++r) {
                float e0 = __expf(sc[mt][0][r] * 0.25f);
                float e1 = (l15 < 4) ? __expf(sc[mt][1][r] * 0.25f) : 0.f;
                float sm = e0 + e1;
                sm += __shfl_xor(sm, 1); sm += __shfl_xor(sm, 2);
                sm += __shfl_xor(sm, 4); sm += __shfl_xor(sm, 8);
                float is = __builtin_amdgcn_rcpf(sm);
                const int row = mt * 16 + lg * 4 + r;
                big[row][l15]      = __float2bfloat16(e0 * is);
                big[row][16 + l15] = __float2bfloat16((l15 < 4) ? e1 * is : 0.f);
            }

        // O_h = P @ V  (V rows >=20 garbage but multiplied by exact-zero P)
#pragma unroll
        for (int mt = 0; mt < 2; ++mt) {
            bf16x8 ap = *(const bf16x8*)&big[mt * 16 + l15][lg * 8];
            f32x4 o = __builtin_amdgcn_mfma_f32_16x16x32_bf16(ap, bv, (f32x4){0,0,0,0}, 0, 0, 0);
            opk[h][mt * 2 + 0] = pk2(o[0], o[1]);
            opk[h][mt * 2 + 1] = pk2(o[2], o[3]);
        }
    }

    // ---- O registers -> big (full 32x64), then out_proj ----
#pragma unroll
    for (int h = 0; h < NH; ++h)
#pragma unroll
        for (int mt = 0; mt < 2; ++mt) {
            const int row0 = mt * 16 + lg * 4;
            const int col = h * 16 + l15;
            big[row0 + 0][col] = us2bf((unsigned short)(opk[h][mt * 2 + 0] & 0xffff));
            big[row0 + 1][col] = us2bf((unsigned short)(opk[h][mt * 2 + 0] >> 16));
            big[row0 + 2][col] = us2bf((unsigned short)(opk[h][mt * 2 + 1] & 0xffff));
            big[row0 + 3][col] = us2bf((unsigned short)(opk[h][mt * 2 + 1] >> 16));
        }

    const __hip_bfloat16* opw_e = opwb + (size_t)e * 64 * 64;
    {
        bf16x8 aO[2][2];
#pragma unroll
        for (int mt = 0; mt < 2; ++mt)
#pragma unroll
            for (int ks = 0; ks < 2; ++ks)
                aO[mt][ks] = *(const bf16x8*)&big[mt * 16 + l15][ks * 32 + lg * 8];
#pragma unroll
        for (int nt = 0; nt < 4; ++nt) {
            const int n = nt * 16 + l15;
            f32x4 po[2] = {{0,0,0,0},{0,0,0,0}};
#pragma unroll
            for (int ks = 0; ks < 2; ++ks) {
                bf16x8 bw = *(const bf16x8*)(opw_e + (size_t)n * 64 + ks * 32 + lg * 8);
#pragma unroll
                for (int mt = 0; mt < 2; ++mt)
                    po[mt] = __builtin_amdgcn_mfma_f32_16x16x32_bf16(aO[mt][ks], bw, po[mt], 0, 0, 0);
            }
            const float lv = ls1[e * 64 + n], ob = opb[e * 64 + n];
#pragma unroll
            for (int mt = 0; mt < 2; ++mt)
#pragma unroll
                for (int r = 0; r < 4; ++r)
                    xsr[mt][nt][r] += lv * (po[mt][r] + ob);
        }
    }

    // ---- rmsnorm2 -> big (rows 20..31 garbage-but-finite, A-path only) ----
    {
        float g2[4];
#pragma unroll
        for (int nt = 0; nt < 4; ++nt) g2[nt] = n2g[e * CD + nt * 16 + l15];
#pragma unroll
        for (int mt = 0; mt < 2; ++mt)
#pragma unroll
            for (int r = 0; r < 4; ++r) {
                const int row = mt * 16 + lg * 4 + r;
                float ss = 0.f;
#pragma unroll
                for (int nt = 0; nt < 4; ++nt) ss += xsr[mt][nt][r] * xsr[mt][nt][r];
                ss += __shfl_xor(ss, 1); ss += __shfl_xor(ss, 2);
                ss += __shfl_xor(ss, 4); ss += __shfl_xor(ss, 8);
                float inv = __builtin_amdgcn_rcpf(sqrtf(ss) * 0.125f + 1e-8f);
#pragma unroll
                for (int nt = 0; nt < 4; ++nt)
                    big[row][nt * 16 + l15] = __float2bfloat16(xsr[mt][nt][r] * inv * g2[nt]);
            }
    }

    // ---- FFN: 8 chunks of 32 hidden cols; hidden double-buffers between
    // big cols 0..31 (even c) and 32..63 (odd c); in-order DS => WAR-safe ----
    {
        bf16x8 af2[2][2];
#pragma unroll
        for (int mt = 0; mt < 2; ++mt)
#pragma unroll
            for (int ks = 0; ks < 2; ++ks)
                af2[mt][ks] = *(const bf16x8*)&big[mt * 16 + l15][ks * 32 + lg * 8];

        f32x4 a2[2][4];
#pragma unroll
        for (int mt = 0; mt < 2; ++mt)
#pragma unroll
            for (int nt = 0; nt < 4; ++nt) a2[mt][nt] = (f32x4){0,0,0,0};

        const __hip_bfloat16* f1_e = fw1b + (size_t)e * 256 * 64;
        const float* fb1_e = fb1 + e * 256;
        const __hip_bfloat16* f2_e = fw2b + (size_t)e * 64 * 256;

#pragma unroll
        for (int c = 0; c < 8; ++c) {
            const int cb = (c & 1) * 32;
#pragma unroll
            for (int ntc = 0; ntc < 2; ++ntc) {
                const int n = c * 32 + ntc * 16 + l15;
                f32x4 hc[2] = {{0,0,0,0},{0,0,0,0}};
#pragma unroll
                for (int ks = 0; ks < 2; ++ks) {
                    bf16x8 bw = *(const bf16x8*)(f1_e + (size_t)n * 64 + ks * 32 + lg * 8);
#pragma unroll
                    for (int mt = 0; mt < 2; ++mt)
                        hc[mt] = __builtin_amdgcn_mfma_f32_16x16x32_bf16(af2[mt][ks], bw, hc[mt], 0, 0, 0);
                }
                const float b1 = fb1_e[n];
#pragma unroll
                for (int mt = 0; mt < 2; ++mt)
#pragma unroll
                    for (int r = 0; r < 4; ++r)
                        big[mt * 16 + lg * 4 + r][cb + ntc * 16 + l15] =
                            __float2bfloat16(fmaxf(hc[mt][r] + b1, 0.f));
            }
            bf16x8 ah[2];
#pragma unroll
            for (int mt = 0; mt < 2; ++mt)
                ah[mt] = *(const bf16x8*)&big[mt * 16 + l15][cb + lg * 8];
#pragma unroll
            for (int nt = 0; nt < 4; ++nt) {
                bf16x8 w2 = *(const bf16x8*)(f2_e + (size_t)(nt * 16 + l15) * 256 + c * 32 + lg * 8);
#pragma unroll
                for (int mt = 0; mt < 2; ++mt)
                    a2[mt][nt] = __builtin_amdgcn_mfma_f32_16x16x32_bf16(ah[mt], w2, a2[mt][nt], 0, 0, 0);
            }
        }

#pragma unroll
        for (int nt = 0; nt < 4; ++nt) {
            const int n = nt * 16 + l15;
            const float lv = ls2[e * 64 + n], b2 = fb2[e * 64 + n];
#pragma unroll
            for (int mt = 0; mt < 2; ++mt)
#pragma unroll
                for (int r = 0; r < 4; ++r)
                    xsr[mt][nt][r] += lv * (a2[mt][nt][r] + b2);
        }
    }

    // ---- stage 8: scatter (bf16, pre-scaled) into big, then coalesced
    // bf16x8 copy to xsf (full 128-B HBM lines, written once) ----
#pragma unroll
    for (int mt = 0; mt < 2; ++mt)
#pragma unroll
        for (int r = 0; r < 4; ++r) {
            const int row = mt * 16 + lg * 4 + r;
            if (row < NC) {
#pragma unroll
                for (int nt = 0; nt < 4; ++nt)
                    big[row][nt * 16 + l15] = __float2bfloat16(wgt * xsr[mt][nt][r]);
            }
        }
    __hip_bfloat16* xo = xsf + (size_t)s * D_SZ;
#pragma unroll
    for (int it = 0; it < 3; ++it) {
        const int c2 = lane + it * 64;
        if (c2 < 160) {
            const int row = c2 >> 3, off = (c2 & 7) * 8;
            bf16x8 v = *(const bf16x8*)&big[row][off];
            *(bf16x8*)(xo + row * 64 + off) = v;
        }
    }
}

// ================= final proj — pair-bucketed, atomic-free =================
// out[b] = (w1 A1)B_e1 + (w2 A2)B_e2 + w1 pb[e1] + w2 pb[e2]; A pre-scaled.
// Rows bucketed by ordered expert pair -> one plain store per out element.
#define PROWP 130

__global__ __launch_bounds__(256) void proj_pair(
    const __hip_bfloat16* __restrict__ xsf, const __hip_bfloat16* __restrict__ pwb,
    const float* __restrict__ pb, const int* __restrict__ poff,
    const int* __restrict__ prA, const int* __restrict__ prB,
    const float* __restrict__ pw1, const float* __restrict__ pw2,
    const int* __restrict__ prow, float* __restrict__ out)
{
    __shared__ short As[8][PROWP][8];
    __shared__ short Bs[8][PROWP][8];
    __shared__ int   sSlot[2][128];
    __shared__ float sW[2][128];
    __shared__ int   sRow[128];

    int mblk = blockIdx.x;
    int p = 0, base = 0, M = 0;
#pragma unroll
    for (int pp = 0; pp < 16; ++pp) {
        int b0 = poff[pp], b1 = poff[pp + 1];
        int nb = (b1 - b0 + 127) >> 7;
        if (p == pp && mblk >= nb) { mblk -= nb; p = pp + 1; }
        else if (p == pp) { base = b0; M = b1 - b0; }
    }
    if (p >= 16) return;
    const int ea = p >> 2, eb = p & 3;

    const int m0 = mblk * 128;
    const int n0 = blockIdx.y * 128;
    const int t = threadIdx.x;
    const int w = t >> 6, lane = t & 63;
    const int wm = (w & 1) * 64, wn = (w >> 1) * 64;
    const int l15 = lane & 15, lg = lane >> 4;

    if (t < 128) {
        int posn = base + m0 + t;
        int sa = prA[posn], sb = prB[posn];
        sSlot[0][t] = min(max(sa, 0), 2 * B_SZ);
        sSlot[1][t] = min(max(sb, 0), 2 * B_SZ);
        sW[0][t] = pw1[posn]; sW[1][t] = pw2[posn];
        sRow[t] = prow[posn];
    }
    __syncthreads();

    f32x4 acc[4][4];
#pragma unroll
    for (int i = 0; i < 4; ++i)
#pragma unroll
        for (int j = 0; j < 4; ++j) acc[i][j] = (f32x4){0.f, 0.f, 0.f, 0.f};

    const int arow0 = t >> 3;          // this thread's 4 staging rows: arow0 + 32*i
    const int akb = t & 7;

#pragma unroll
    for (int ph = 0; ph < 2; ++ph) {
        const __hip_bfloat16* Bg = pwb + (size_t)(ph ? eb : ea) * D_SZ * D_SZ + (size_t)n0 * D_SZ;
        int aslot[4];
#pragma unroll
        for (int i = 0; i < 4; ++i) aslot[i] = sSlot[ph][arow0 + 32 * i];

        for (int kt = 0; kt < D_SZ; kt += 64) {
            __syncthreads();
#pragma unroll
            for (int i = 0; i < 4; ++i) {
                int row = arow0 + 32 * i;
                *(uint4*)&As[akb][row][0] =
                    *(const uint4*)(xsf + (size_t)aslot[i] * D_SZ + kt + akb * 8);
                *(uint4*)&Bs[akb][row][0] =
                    *(const uint4*)(Bg + (size_t)row * D_SZ + kt + akb * 8);
            }
            __syncthreads();
#pragma unroll
            for (int ks = 0; ks < 2; ++ks) {
                int kb = ks * 4 + lg;
                bf16x8 af[4], bfr[4];
#pragma unroll
                for (int ti = 0; ti < 4; ++ti) af[ti]  = *(const bf16x8*)&As[kb][wm + ti * 16 + l15][0];
#pragma unroll
                for (int tj = 0; tj < 4; ++tj) bfr[tj] = *(const bf16x8*)&Bs[kb][wn + tj * 16 + l15][0];
#pragma unroll
                for (int ti = 0; ti < 4; ++ti)
#pragma unroll
                    for (int tj = 0; tj < 4; ++tj)
                        acc[ti][tj] = __builtin_amdgcn_mfma_f32_16x16x32_bf16(
                            af[ti], bfr[tj], acc[ti][tj], 0, 0, 0);
            }
        }
    }

    float pbva[4], pbvb[4];
#pragma unroll
    for (int tj = 0; tj < 4; ++tj) {
        int nc = n0 + wn + tj * 16 + l15;
        pbva[tj] = pb[(size_t)ea * D_SZ + nc];
        pbvb[tj] = pb[(size_t)eb * D_SZ + nc];
    }

#pragma unroll
    for (int ti = 0; ti < 4; ++ti) {
#pragma unroll
        for (int r = 0; r < 4; ++r) {
            int m = wm + ti * 16 + lg * 4 + r;
            if (m0 + m < M) {
                float w1 = sW[0][m], w2 = sW[1][m];
                float* orow = out + (size_t)sRow[m] * D_SZ + n0 + wn + l15;
#pragma unroll
                for (int tj = 0; tj < 4; ++tj)
                    orow[tj * 16] = acc[ti][tj][r] + w1 * pbva[tj] + w2 * pbvb[tj];
            }
        }
    }
}

// ================= host launcher =================
extern "C" void kernel_launch(void* const* d_in, const int* in_sizes, int n_in,
                              void* d_out, int out_size, void* d_ws, size_t ws_size,
                              hipStream_t stream)
{
    const float* x   = (const float*)d_in[0];
    const float* gw1 = (const float*)d_in[1];
    const float* gb1 = (const float*)d_in[2];
    const float* gw2 = (const float*)d_in[3];
    const float* gb2 = (const float*)d_in[4];
    const float* pos = (const float*)d_in[5];
    const float* n1g = (const float*)d_in[6];
    const float* ipw = (const float*)d_in[7];
    const float* ipb = (const float*)d_in[8];
    const float* opw = (const float*)d_in[9];
    const float* opb = (const float*)d_in[10];
    const float* ls1 = (const float*)d_in[11];
    const float* n2g = (const float*)d_in[12];
    const float* fw1 = (const float*)d_in[13];
    const float* fb1 = (const float*)d_in[14];
    const float* fw2 = (const float*)d_in[15];
    const float* fb2 = (const float*)d_in[16];
    const float* ls2 = (const float*)d_in[17];
    const float* pw  = (const float*)d_in[18];
    const float* pb  = (const float*)d_in[19];

    float* out = (float*)d_out;

    char* ws = (char*)d_ws;
    int*   cnt      = (int*)(ws + 0);
    int*   pcnt     = (int*)(ws + 16);
    int*   offA     = (int*)(ws + 80);
    int*   poff     = (int*)(ws + 112);
    int*   topi     = (int*)(ws + WS_TOPI);
    float* topw     = (float*)(ws + WS_TOPW);
    int*   idx_list = (int*)(ws + WS_IDX);
    float* wgt_list = (float*)(ws + WS_WGT);
    int*   er0      = (int*)(ws + WS_ER0);
    int*   er1      = (int*)(ws + WS_ER1);
    int*   prk      = (int*)(ws + WS_PRK);
    int*   bbe      = (int*)(ws + WS_BBE);
    int*   bbp      = (int*)(ws + WS_BBP);
    int*   prA      = (int*)(ws + WS_PRA);
    int*   prB      = (int*)(ws + WS_PRB);
    float* pw1      = (float*)(ws + WS_PW1);
    float* pw2      = (float*)(ws + WS_PW2);
    int*   prow     = (int*)(ws + WS_PRW);
    __hip_bfloat16* xsf  = (__hip_bfloat16*)(ws + WS_XSF);
    __hip_bfloat16* pwb  = (__hip_bfloat16*)(ws + WS_PWB);
    __hip_bfloat16* ipwb = (__hip_bfloat16*)(ws + WS_IPWB);
    __hip_bfloat16* opwb = (__hip_bfloat16*)(ws + WS_OPWB);
    __hip_bfloat16* fw1b = (__hip_bfloat16*)(ws + WS_FW1B);
    __hip_bfloat16* fw2b = (__hip_bfloat16*)(ws + WS_FW2B);

    // zero counters + aux/load slots only (main out region is fully overwritten)
    hipMemsetAsync(d_ws, 0, 256, stream);
    hipMemsetAsync(out + (size_t)B_SZ * D_SZ, 0, 5 * sizeof(float), stream);

    float* load_out = out + (size_t)B_SZ * D_SZ + 1;

    convert_pw<<<NE * D_SZ * D_SZ / (256 * 8), 256, 0, stream>>>(pw, pwb);
    convert_small<<<(N_IPW + N_OPW + N_FW1 + N_FW2) / (256 * 8), 256, 0, stream>>>(
        ipw, opw, fw1, fw2, ipwb, opwb, fw1b, fw2b);
    gate_kernel<<<B_SZ, 64, 0, stream>>>(x, gw1, gb1, gw2, gb2, topi, topw);
    count_kernel<<<B_SZ / 256, 256, 0, stream>>>(topi, cnt, pcnt, er0, er1, prk, bbe, bbp);
    offsets_kernel<<<1, 64, 0, stream>>>(cnt, pcnt, offA, poff, load_out);
    fill_kernel<<<B_SZ / 256, 256, 0, stream>>>(topi, topw, offA, poff, er0, er1, prk,
                                                bbe, bbp, idx_list, wgt_list,
                                                prA, prB, pw1, pw2, prow);
    expert_inner<<<(2 * B_SZ) / 4, 256, 0, stream>>>(x, pos, n1g, ipwb, ipb, opwb, opb, ls1,
                                                     n2g, fw1b, fb1, fw2b, fb2, ls2,
                                                     offA, idx_list, wgt_list, xsf);
    proj_pair<<<dim3(96, D_SZ / 128), 256, 0, stream>>>(
        xsf, pwb, pb, poff, prA, prB, pw1, pw2, prow, out);
}

// Round 5
// 508.443 us; speedup vs baseline: 1.1206x; 1.1206x over previous
//
#include <hip/hip_runtime.h>
#include <hip/hip_bf16.h>
#include <math.h>

#define B_SZ 8192
#define D_SZ 1280
#define NE   4
#define NC   20
#define CD   64
#define NH   4
#define HD   16
#define FF   256

typedef __attribute__((ext_vector_type(8))) short bf16x8;
typedef __attribute__((ext_vector_type(4))) float f32x4;

__device__ inline unsigned int pk2(float lo, float hi) {
    union { __hip_bfloat16 h; unsigned short s; } a, b;
    a.h = __float2bfloat16(lo); b.h = __float2bfloat16(hi);
    return (unsigned int)a.s | ((unsigned int)b.s << 16);
}

// ---------------- workspace layout (bytes) ----------------
// header: cnt[4]@0, pcnt[16]@16, offA[8]@80, poff[20]@112  (memset first 256 B)
#define WS_TOPI   256
#define WS_TOPW   (WS_TOPI + 2*B_SZ*4)
#define WS_IDX    (WS_TOPW + 2*B_SZ*4)
#define WS_WGT    (WS_IDX  + 2*B_SZ*4)
#define WS_ER0    (WS_WGT  + 2*B_SZ*4)
#define WS_ER1    (WS_ER0  + B_SZ*4)
#define WS_PRK    (WS_ER1  + B_SZ*4)
#define WS_BBE    (WS_PRK  + B_SZ*4)
#define WS_BBP    (WS_BBE  + 32*4*4)
#define WS_PRA    (WS_BBP  + 32*16*4)
#define WS_PRB    (WS_PRA  + (B_SZ+128)*4)
#define WS_PW1    (WS_PRB  + (B_SZ+128)*4)
#define WS_PW2    (WS_PW1  + (B_SZ+128)*4)
#define WS_PRW    (WS_PW2  + (B_SZ+128)*4)
#define WS_XSF    532480
#define XSF_ROWS  (2*B_SZ + 128)
#define WS_PWB    (WS_XSF + (size_t)XSF_ROWS * D_SZ * 2)
#define WS_IPWB   (WS_PWB  + (size_t)NE * D_SZ * D_SZ * 2)
#define WS_OPWB   (WS_IPWB + (size_t)NE * 192 * 64 * 2)
#define WS_FW1B   (WS_OPWB + (size_t)NE * 64 * 64 * 2)
#define WS_FW2B   (WS_FW1B + (size_t)NE * 256 * 64 * 2)

// ================= weight conversion =================
__global__ __launch_bounds__(256) void convert_pw(const float* __restrict__ pw,
                                                  __hip_bfloat16* __restrict__ pwb)
{
    size_t i = ((size_t)blockIdx.x * 256 + threadIdx.x) * 8;
    float4 a = *(const float4*)(pw + i);
    float4 b = *(const float4*)(pw + i + 4);
    __hip_bfloat16 h[8];
    h[0] = __float2bfloat16(a.x); h[1] = __float2bfloat16(a.y);
    h[2] = __float2bfloat16(a.z); h[3] = __float2bfloat16(a.w);
    h[4] = __float2bfloat16(b.x); h[5] = __float2bfloat16(b.y);
    h[6] = __float2bfloat16(b.z); h[7] = __float2bfloat16(b.w);
    *(uint4*)(pwb + i) = *(uint4*)h;
}

// convert_small now folds LayerScale into out_proj (ls1) and ffn2 (ls2)
// weights: both scales are per-OUTPUT-row -> exact to bake in (B-fragment
// columns are lane-uniform). Biases are added separately in expert_inner.
#define N_IPW (NE*192*64)
#define N_OPW (NE*64*64)
#define N_FW1 (NE*256*64)
#define N_FW2 (NE*64*256)
__global__ __launch_bounds__(256) void convert_small(
    const float* __restrict__ ipw, const float* __restrict__ opw,
    const float* __restrict__ fw1, const float* __restrict__ fw2,
    const float* __restrict__ ls1, const float* __restrict__ ls2,
    __hip_bfloat16* __restrict__ ipwb, __hip_bfloat16* __restrict__ opwb,
    __hip_bfloat16* __restrict__ fw1b, __hip_bfloat16* __restrict__ fw2b)
{
    size_t i = ((size_t)blockIdx.x * 256 + threadIdx.x) * 8;
    const float* src; __hip_bfloat16* dst; size_t off;
    float scale = 1.f;
    if (i < N_IPW)                       { src = ipw; dst = ipwb; off = i; }
    else if (i < N_IPW + N_OPW)          {
        off = i - N_IPW; src = opw; dst = opwb;
        int e = (int)(off >> 12); int n = (int)((off >> 6) & 63);
        scale = ls1[e * 64 + n];
    }
    else if (i < N_IPW + N_OPW + N_FW1)  { src = fw1; dst = fw1b; off = i - N_IPW - N_OPW; }
    else {
        off = i - N_IPW - N_OPW - N_FW1; src = fw2; dst = fw2b;
        int e = (int)(off >> 14); int n = (int)((off >> 8) & 63);
        scale = ls2[e * 64 + n];
    }
    float4 a = *(const float4*)(src + off);
    float4 b = *(const float4*)(src + off + 4);
    __hip_bfloat16 h[8];
    h[0] = __float2bfloat16(a.x * scale); h[1] = __float2bfloat16(a.y * scale);
    h[2] = __float2bfloat16(a.z * scale); h[3] = __float2bfloat16(a.w * scale);
    h[4] = __float2bfloat16(b.x * scale); h[5] = __float2bfloat16(b.y * scale);
    h[6] = __float2bfloat16(b.z * scale); h[7] = __float2bfloat16(b.w * scale);
    *(uint4*)(dst + off) = *(uint4*)h;
}

// ================= gate (no atomics) =================
__global__ __launch_bounds__(64) void gate_kernel(
    const float* __restrict__ x, const float* __restrict__ gw1, const float* __restrict__ gb1,
    const float* __restrict__ gw2, const float* __restrict__ gb2,
    int* __restrict__ topi, float* __restrict__ topw)
{
    const int b = blockIdx.x;
    const int lane = threadIdx.x;
    float acc[16];
#pragma unroll
    for (int j = 0; j < 16; ++j) acc[j] = 0.f;
    const float* xr = x + (size_t)b * D_SZ;
    for (int t = 0; t < NC; ++t) {
        float xv = xr[t * 64 + lane];
#pragma unroll
        for (int j = 0; j < 16; ++j) acc[j] += xv * gw1[j * D_SZ + t * 64 + lane];
    }
#pragma unroll
    for (int j = 0; j < 16; ++j) {
        acc[j] += __shfl_xor(acc[j], 32, 64);
        acc[j] += __shfl_xor(acc[j], 16, 64);
        acc[j] += __shfl_xor(acc[j], 8, 64);
        acc[j] += __shfl_xor(acc[j], 4, 64);
        acc[j] += __shfl_xor(acc[j], 2, 64);
        acc[j] += __shfl_xor(acc[j], 1, 64);
    }
    if (lane == 0) {
        float h[16];
#pragma unroll
        for (int j = 0; j < 16; ++j) h[j] = tanhf(acc[j] + gb1[j]);
        float l[4];
#pragma unroll
        for (int e = 0; e < 4; ++e) {
            float sv = gb2[e];
#pragma unroll
            for (int j = 0; j < 16; ++j) sv += h[j] * gw2[e * 16 + j];
            l[e] = sv;
        }
        float m = fmaxf(fmaxf(l[0], l[1]), fmaxf(l[2], l[3]));
        float p[4];
        float sum = 0.f;
#pragma unroll
        for (int e = 0; e < 4; ++e) { p[e] = expf(l[e] - m); sum += p[e]; }
#pragma unroll
        for (int e = 0; e < 4; ++e) p[e] /= sum;
        int i1 = 0;
#pragma unroll
        for (int e = 1; e < 4; ++e) if (p[e] > p[i1]) i1 = e;
        int i2 = (i1 == 0) ? 1 : 0;
#pragma unroll
        for (int e = 0; e < 4; ++e) if (e != i1 && p[e] > p[i2]) i2 = e;
        float s1 = p[i1], s2 = p[i2];
        float denom = s1 + s2 + 1e-6f;
        topi[b * 2 + 0] = i1;
        topi[b * 2 + 1] = i2;
        topw[b * 2 + 0] = s1 / denom;
        topw[b * 2 + 1] = s2 / denom;
    }
}

// ================= routing: block-aggregated count =================
__global__ __launch_bounds__(256) void count_kernel(
    const int* __restrict__ topi,
    int* __restrict__ cnt, int* __restrict__ pcnt,
    int* __restrict__ er0, int* __restrict__ er1, int* __restrict__ prk,
    int* __restrict__ bbe, int* __restrict__ bbp)
{
    __shared__ int he[4], hp[16];
    const int t = threadIdx.x;
    const int blk = blockIdx.x;
    const int b = blk * 256 + t;
    if (t < 4) he[t] = 0;
    if (t < 16) hp[t] = 0;
    __syncthreads();
    int e0 = topi[b * 2], e1 = topi[b * 2 + 1];
    er0[b] = atomicAdd(&he[e0], 1);
    er1[b] = atomicAdd(&he[e1], 1);
    prk[b] = atomicAdd(&hp[e0 * 4 + e1], 1);
    __syncthreads();
    if (t < 4)  bbe[blk * 4 + t]  = atomicAdd(&cnt[t], he[t]);
    if (t < 16) bbp[blk * 16 + t] = atomicAdd(&pcnt[t], hp[t]);
}

__global__ void offsets_kernel(const int* __restrict__ cnt, const int* __restrict__ pcnt,
                               int* __restrict__ offA, int* __restrict__ poff,
                               float* __restrict__ load_out)
{
    if (threadIdx.x == 0 && blockIdx.x == 0) {
        int a = 0;
#pragma unroll
        for (int e = 0; e < 4; ++e) { offA[e] = a; a += cnt[e]; }
        offA[4] = a;
        int q = 0;
#pragma unroll
        for (int p = 0; p < 16; ++p) { poff[p] = q; q += pcnt[p]; }
        poff[16] = q;
#pragma unroll
        for (int e = 0; e < 4; ++e) load_out[e] = (float)cnt[e];
    }
}

__global__ __launch_bounds__(256) void fill_kernel(
    const int* __restrict__ topi, const float* __restrict__ topw,
    const int* __restrict__ offA, const int* __restrict__ poff,
    const int* __restrict__ er0, const int* __restrict__ er1, const int* __restrict__ prk,
    const int* __restrict__ bbe, const int* __restrict__ bbp,
    int* __restrict__ idx_list, float* __restrict__ wgt_list,
    int* __restrict__ prA, int* __restrict__ prB,
    float* __restrict__ pw1, float* __restrict__ pw2, int* __restrict__ prow)
{
    const int b = blockIdx.x * 256 + threadIdx.x;
    const int blk = blockIdx.x;
    int e0 = topi[b * 2], e1 = topi[b * 2 + 1];
    float w0 = topw[b * 2], w1 = topw[b * 2 + 1];
    int slot0 = offA[e0] + bbe[blk * 4 + e0] + er0[b];
    int slot1 = offA[e1] + bbe[blk * 4 + e1] + er1[b];
    idx_list[slot0] = b; wgt_list[slot0] = w0;
    idx_list[slot1] = b; wgt_list[slot1] = w1;
    int p = e0 * 4 + e1;
    int pos = poff[p] + bbp[blk * 16 + p] + prk[b];
    prA[pos] = slot0; prB[pos] = slot1;
    pw1[pos] = w0; pw2[pos] = w1; prow[pos] = b;
}

// ================= expert inner — wave-per-token, v5 ==================
// v5 vs v4 (goal: genuinely fit 128 VGPR at (256,4), no scratch spill):
// - LayerScale baked into opwb/fw2b at convert time -> out_proj and ffn2
//   MFMAs accumulate DIRECTLY into xsr (residual is the MFMA C operand).
//   Deletes a2[2][4] (-32 VGPR) and per-head O register bank opk (-16).
// - out_proj done incrementally per head: O_h staged through big cols
//   32..47 (dead during attention), K=16-masked MFMA against the head's
//   weight block, C-chained on xsr.
// - Q/K computed before V in the head loop (lower peak accumulators).
// Spill detector: FETCH/WRITE must return to ~45/~41 MB.
__global__ __launch_bounds__(256, 4) void expert_inner(
    const float* __restrict__ x, const float* __restrict__ pos,
    const float* __restrict__ n1g,
    const __hip_bfloat16* __restrict__ ipwb, const float* __restrict__ ipb,
    const __hip_bfloat16* __restrict__ opwb, const float* __restrict__ opb,
    const float* __restrict__ ls1, const float* __restrict__ n2g,
    const __hip_bfloat16* __restrict__ fw1b, const float* __restrict__ fb1,
    const __hip_bfloat16* __restrict__ fw2b, const float* __restrict__ fb2,
    const float* __restrict__ ls2,
    const int* __restrict__ offA, const int* __restrict__ idx_list,
    const float* __restrict__ wgt_list,
    __hip_bfloat16* __restrict__ xsf)
{
    __shared__ __hip_bfloat16 s_big[4][32][72];   // 4*4608 = 18432 B

    const int t = threadIdx.x;
    const int w = t >> 6;
    const int lane = t & 63;
    const int l15 = lane & 15, lg = lane >> 4;
    const int s = blockIdx.x * 4 + w;
    const int e = (s >= offA[1]) + (s >= offA[2]) + (s >= offA[3]);
    const int b = idx_list[s];
    const float wgt = wgt_list[s];

    __hip_bfloat16 (* const big)[72] = s_big[w];

    const float* xg = x + (size_t)b * D_SZ;
    const float* pg = pos + (size_t)e * D_SZ;
    const __hip_bfloat16* ipw_e = ipwb + (size_t)e * 192 * 64;
    const float* ipb_e = ipb + e * 192;

    f32x4 xsr[2][4];   // residual, C-layout (row = mt*16+lg*4+r, col = nt*16+l15)

    // ---- stage 1: load x+pos, rmsnorm1 -> big (rows 20..31 exact zeros) ----
#pragma unroll
    for (int mt = 0; mt < 2; ++mt)
#pragma unroll
        for (int r = 0; r < 4; ++r) {
            const int row = mt * 16 + lg * 4 + r;
#pragma unroll
            for (int nt = 0; nt < 4; ++nt) {
                float v = 0.f;
                if (row < NC) v = xg[row * 64 + nt * 16 + l15] + pg[row * 64 + nt * 16 + l15];
                xsr[mt][nt][r] = v;
            }
        }
    {
        float g1[4];
#pragma unroll
        for (int nt = 0; nt < 4; ++nt) g1[nt] = n1g[e * CD + nt * 16 + l15];
#pragma unroll
        for (int mt = 0; mt < 2; ++mt)
#pragma unroll
            for (int r = 0; r < 4; ++r) {
                const int row = mt * 16 + lg * 4 + r;
                float ss = 0.f;
#pragma unroll
                for (int nt = 0; nt < 4; ++nt) ss += xsr[mt][nt][r] * xsr[mt][nt][r];
                ss += __shfl_xor(ss, 1); ss += __shfl_xor(ss, 2);
                ss += __shfl_xor(ss, 4); ss += __shfl_xor(ss, 8);
                float inv = __builtin_amdgcn_rcpf(sqrtf(ss) * 0.125f + 1e-8f);
#pragma unroll
                for (int nt = 0; nt < 4; ++nt)
                    big[row][nt * 16 + l15] = __float2bfloat16(xsr[mt][nt][r] * inv * g1[nt]);
            }
    }

    // A-fragments of normed x (register-resident for the whole attention)
    bf16x8 af[2][2];
#pragma unroll
    for (int mt = 0; mt < 2; ++mt)
#pragma unroll
        for (int ks = 0; ks < 2; ++ks)
            af[mt][ks] = *(const bf16x8*)&big[mt * 16 + l15][ks * 32 + lg * 8];

    const __hip_bfloat16* opw_e = opwb + (size_t)e * 64 * 64;   // pre-scaled by ls1
    const bf16x8 zf = {0,0,0,0,0,0,0,0};

    // ---- stages 2..4: per-head qkv -> attention -> incremental out_proj ----
#pragma unroll
    for (int h = 0; h < NH; ++h) {
        const int nq = h * 16 + l15;

        // Q, K
        f32x4 qa[2] = {{0,0,0,0},{0,0,0,0}};
        f32x4 ka[2] = {{0,0,0,0},{0,0,0,0}};
#pragma unroll
        for (int ks = 0; ks < 2; ++ks) {
            bf16x8 wq = *(const bf16x8*)(ipw_e + (size_t)(nq) * 64 + ks * 32 + lg * 8);
            bf16x8 wk = *(const bf16x8*)(ipw_e + (size_t)(64 + nq) * 64 + ks * 32 + lg * 8);
#pragma unroll
            for (int mt = 0; mt < 2; ++mt) {
                qa[mt] = __builtin_amdgcn_mfma_f32_16x16x32_bf16(af[mt][ks], wq, qa[mt], 0, 0, 0);
                ka[mt] = __builtin_amdgcn_mfma_f32_16x16x32_bf16(af[mt][ks], wk, ka[mt], 0, 0, 0);
            }
        }
        const float biq = ipb_e[nq], bik = ipb_e[64 + nq];
#pragma unroll
        for (int mt = 0; mt < 2; ++mt)
#pragma unroll
            for (int r = 0; r < 4; ++r) {
                const int row = mt * 16 + lg * 4 + r;
                big[row][l15]      = __float2bfloat16(qa[mt][r] + biq);
                big[row][16 + l15] = __float2bfloat16(ka[mt][r] + bik);
            }

        // V
        f32x4 va[2] = {{0,0,0,0},{0,0,0,0}};
#pragma unroll
        for (int ks = 0; ks < 2; ++ks) {
            bf16x8 wv = *(const bf16x8*)(ipw_e + (size_t)(128 + nq) * 64 + ks * 32 + lg * 8);
#pragma unroll
            for (int mt = 0; mt < 2; ++mt)
                va[mt] = __builtin_amdgcn_mfma_f32_16x16x32_bf16(af[mt][ks], wv, va[mt], 0, 0, 0);
        }
        const float biv = ipb_e[128 + nq];

        // V B-fragment via lane permutation (no LDS round-trip):
        // lane (l15,lg) needs V[k=lg*8+j][d=l15]; source pairs live in lanes
        // (2*(lg&1))*16+l15 (j0..3) and +16 (j4..7); mt half chosen by lg>=2.
        unsigned int vp0[2], vp1[2];
#pragma unroll
        for (int mt = 0; mt < 2; ++mt) {
            vp0[mt] = pk2(va[mt][0] + biv, va[mt][1] + biv);
            vp1[mt] = pk2(va[mt][2] + biv, va[mt][3] + biv);
        }
        const int aA = (((lg & 1) * 32) + l15) * 4;
        const int aB = aA + 64;
        int d0a = __builtin_amdgcn_ds_bpermute(aA, (int)vp0[0]);
        int d0b = __builtin_amdgcn_ds_bpermute(aA, (int)vp0[1]);
        int d1a = __builtin_amdgcn_ds_bpermute(aA, (int)vp1[0]);
        int d1b = __builtin_amdgcn_ds_bpermute(aA, (int)vp1[1]);
        int d2a = __builtin_amdgcn_ds_bpermute(aB, (int)vp0[0]);
        int d2b = __builtin_amdgcn_ds_bpermute(aB, (int)vp0[1]);
        int d3a = __builtin_amdgcn_ds_bpermute(aB, (int)vp1[0]);
        int d3b = __builtin_amdgcn_ds_bpermute(aB, (int)vp1[1]);
        const bool hi2 = (lg >= 2);
        union { int i[4]; bf16x8 v; } uv;
        uv.i[0] = hi2 ? d0b : d0a;
        uv.i[1] = hi2 ? d1b : d1a;
        uv.i[2] = hi2 ? d2b : d2a;
        uv.i[3] = hi2 ? d3b : d3a;
        const bf16x8 bv = uv.v;

        // S = Q K^T (head_dim 16 -> lg>=2 lanes zero)
        bf16x8 aq[2], bk[2];
#pragma unroll
        for (int mt = 0; mt < 2; ++mt) {
            aq[mt] = zf;
            if (lg < 2) aq[mt] = *(const bf16x8*)&big[mt * 16 + l15][lg * 8];
        }
#pragma unroll
        for (int nt = 0; nt < 2; ++nt) {
            bk[nt] = zf;
            if (lg < 2) bk[nt] = *(const bf16x8*)&big[nt * 16 + l15][16 + lg * 8];
        }
        f32x4 sc[2][2];
#pragma unroll
        for (int mt = 0; mt < 2; ++mt)
#pragma unroll
            for (int nt = 0; nt < 2; ++nt)
                sc[mt][nt] = __builtin_amdgcn_mfma_f32_16x16x32_bf16(aq[mt], bk[nt], (f32x4){0,0,0,0}, 0, 0, 0);

        // softmax (no max-subtract: |S|*0.25 tiny with 0.02-scale weights);
        // keys 20..31 excluded via l15<4 mask; P overwrites big cols 0..31.
#pragma unroll
        for (int mt = 0; mt < 2; ++mt)
#pragma unroll
            for (int r = 0; r < 4; ++r) {
                float e0 = __expf(sc[mt][0][r] * 0.25f);
                float e1 = (l15 < 4) ? __expf(sc[mt][1][r] * 0.25f) : 0.f;
                float sm = e0 + e1;
                sm += __shfl_xor(sm, 1); sm += __shfl_xor(sm, 2);
                sm += __shfl_xor(sm, 4); sm += __shfl_xor(sm, 8);
                float is = __builtin_amdgcn_rcpf(sm);
                const int row = mt * 16 + lg * 4 + r;
                big[row][l15]      = __float2bfloat16(e0 * is);
                big[row][16 + l15] = __float2bfloat16((l15 < 4) ? e1 * is : 0.f);
            }

        // O_h = P @ V -> staged through big cols 32..47 (dead region)
#pragma unroll
        for (int mt = 0; mt < 2; ++mt) {
            bf16x8 ap = *(const bf16x8*)&big[mt * 16 + l15][lg * 8];
            f32x4 o = __builtin_amdgcn_mfma_f32_16x16x32_bf16(ap, bv, (f32x4){0,0,0,0}, 0, 0, 0);
#pragma unroll
            for (int r = 0; r < 4; ++r)
                big[mt * 16 + lg * 4 + r][32 + l15] = __float2bfloat16(o[r]);
        }

        // incremental out_proj: xsr += O_h @ (ls1-scaled opw head-block)
        bf16x8 aOh[2];
#pragma unroll
        for (int mt = 0; mt < 2; ++mt) {
            aOh[mt] = zf;
            if (lg < 2) aOh[mt] = *(const bf16x8*)&big[mt * 16 + l15][32 + lg * 8];
        }
#pragma unroll
        for (int nt = 0; nt < 4; ++nt) {
            bf16x8 bw = zf;
            if (lg < 2) bw = *(const bf16x8*)(opw_e + (size_t)(nt * 16 + l15) * 64 + h * 16 + lg * 8);
#pragma unroll
            for (int mt = 0; mt < 2; ++mt)
                xsr[mt][nt] = __builtin_amdgcn_mfma_f32_16x16x32_bf16(aOh[mt], bw, xsr[mt][nt], 0, 0, 0);
        }
    }

    // out_proj bias (ls1-scaled), then rmsnorm2 -> big
    {
        float g2[4];
#pragma unroll
        for (int nt = 0; nt < 4; ++nt) {
            const int n = nt * 16 + l15;
            const float ob1 = ls1[e * 64 + n] * opb[e * 64 + n];
            g2[nt] = n2g[e * CD + n];
#pragma unroll
            for (int mt = 0; mt < 2; ++mt)
#pragma unroll
                for (int r = 0; r < 4; ++r) xsr[mt][nt][r] += ob1;
        }
#pragma unroll
        for (int mt = 0; mt < 2; ++mt)
#pragma unroll
            for (int r = 0; r < 4; ++r) {
                const int row = mt * 16 + lg * 4 + r;
                float ss = 0.f;
#pragma unroll
                for (int nt = 0; nt < 4; ++nt) ss += xsr[mt][nt][r] * xsr[mt][nt][r];
                ss += __shfl_xor(ss, 1); ss += __shfl_xor(ss, 2);
                ss += __shfl_xor(ss, 4); ss += __shfl_xor(ss, 8);
                float inv = __builtin_amdgcn_rcpf(sqrtf(ss) * 0.125f + 1e-8f);
#pragma unroll
                for (int nt = 0; nt < 4; ++nt)
                    big[row][nt * 16 + l15] = __float2bfloat16(xsr[mt][nt][r] * inv * g2[nt]);
            }
    }

    // ---- FFN: 8 chunks of 32 hidden cols; hidden double-buffers between
    // big cols 0..31 (even c) / 32..63 (odd c); ffn2 (ls2-scaled) MFMAs
    // accumulate directly into xsr; in-order DS => WAR-safe ----
    {
        bf16x8 af2[2][2];
#pragma unroll
        for (int mt = 0; mt < 2; ++mt)
#pragma unroll
            for (int ks = 0; ks < 2; ++ks)
                af2[mt][ks] = *(const bf16x8*)&big[mt * 16 + l15][ks * 32 + lg * 8];

        const __hip_bfloat16* f1_e = fw1b + (size_t)e * 256 * 64;
        const float* fb1_e = fb1 + e * 256;
        const __hip_bfloat16* f2_e = fw2b + (size_t)e * 64 * 256;

#pragma unroll
        for (int c = 0; c < 8; ++c) {
            const int cb = (c & 1) * 32;
#pragma unroll
            for (int ntc = 0; ntc < 2; ++ntc) {
                const int n = c * 32 + ntc * 16 + l15;
                f32x4 hc[2] = {{0,0,0,0},{0,0,0,0}};
#pragma unroll
                for (int ks = 0; ks < 2; ++ks) {
                    bf16x8 bw = *(const bf16x8*)(f1_e + (size_t)n * 64 + ks * 32 + lg * 8);
#pragma unroll
                    for (int mt = 0; mt < 2; ++mt)
                        hc[mt] = __builtin_amdgcn_mfma_f32_16x16x32_bf16(af2[mt][ks], bw, hc[mt], 0, 0, 0);
                }
                const float b1 = fb1_e[n];
#pragma unroll
                for (int mt = 0; mt < 2; ++mt)
#pragma unroll
                    for (int r = 0; r < 4; ++r)
                        big[mt * 16 + lg * 4 + r][cb + ntc * 16 + l15] =
                            __float2bfloat16(fmaxf(hc[mt][r] + b1, 0.f));
            }
            bf16x8 ah[2];
#pragma unroll
            for (int mt = 0; mt < 2; ++mt)
                ah[mt] = *(const bf16x8*)&big[mt * 16 + l15][cb + lg * 8];
#pragma unroll
            for (int nt = 0; nt < 4; ++nt) {
                bf16x8 w2 = *(const bf16x8*)(f2_e + (size_t)(nt * 16 + l15) * 256 + c * 32 + lg * 8);
#pragma unroll
                for (int mt = 0; mt < 2; ++mt)
                    xsr[mt][nt] = __builtin_amdgcn_mfma_f32_16x16x32_bf16(ah[mt], w2, xsr[mt][nt], 0, 0, 0);
            }
        }

        // ffn2 bias (ls2-scaled)
#pragma unroll
        for (int nt = 0; nt < 4; ++nt) {
            const int n = nt * 16 + l15;
            const float b2s = ls2[e * 64 + n] * fb2[e * 64 + n];
#pragma unroll
            for (int mt = 0; mt < 2; ++mt)
#pragma unroll
                for (int r = 0; r < 4; ++r) xsr[mt][nt][r] += b2s;
        }
    }

    // ---- stage 8: scatter (bf16, pre-scaled by combine weight) into big,
    // then coalesced bf16x8 copy to xsf (full HBM lines, written once) ----
#pragma unroll
    for (int mt = 0; mt < 2; ++mt)
#pragma unroll
        for (int r = 0; r < 4; ++r) {
            const int row = mt * 16 + lg * 4 + r;
            if (row < NC) {
#pragma unroll
                for (int nt = 0; nt < 4; ++nt)
                    big[row][nt * 16 + l15] = __float2bfloat16(wgt * xsr[mt][nt][r]);
            }
        }
    __hip_bfloat16* xo = xsf + (size_t)s * D_SZ;
#pragma unroll
    for (int it = 0; it < 3; ++it) {
        const int c2 = lane + it * 64;
        if (c2 < 160) {
            const int row = c2 >> 3, off = (c2 & 7) * 8;
            bf16x8 v = *(const bf16x8*)&big[row][off];
            *(bf16x8*)(xo + row * 64 + off) = v;
        }
    }
}

// ================= final proj — pair-bucketed, atomic-free =================
// out[b] = (w1 A1)B_e1 + (w2 A2)B_e2 + w1 pb[e1] + w2 pb[e2]; A pre-scaled.
// Rows bucketed by ordered expert pair -> one plain store per out element.
#define PROWP 130

__global__ __launch_bounds__(256) void proj_pair(
    const __hip_bfloat16* __restrict__ xsf, const __hip_bfloat16* __restrict__ pwb,
    const float* __restrict__ pb, const int* __restrict__ poff,
    const int* __restrict__ prA, const int* __restrict__ prB,
    const float* __restrict__ pw1, const float* __restrict__ pw2,
    const int* __restrict__ prow, float* __restrict__ out)
{
    __shared__ short As[8][PROWP][8];
    __shared__ short Bs[8][PROWP][8];
    __shared__ int   sSlot[2][128];
    __shared__ float sW[2][128];
    __shared__ int   sRow[128];

    int mblk = blockIdx.x;
    int p = 0, base = 0, M = 0;
#pragma unroll
    for (int pp = 0; pp < 16; ++pp) {
        int b0 = poff[pp], b1 = poff[pp + 1];
        int nb = (b1 - b0 + 127) >> 7;
        if (p == pp && mblk >= nb) { mblk -= nb; p = pp + 1; }
        else if (p == pp) { base = b0; M = b1 - b0; }
    }
    if (p >= 16) return;
    const int ea = p >> 2, eb = p & 3;

    const int m0 = mblk * 128;
    const int n0 = blockIdx.y * 128;
    const int t = threadIdx.x;
    const int w = t >> 6, lane = t & 63;
    const int wm = (w & 1) * 64, wn = (w >> 1) * 64;
    const int l15 = lane & 15, lg = lane >> 4;

    if (t < 128) {
        int posn = base + m0 + t;
        int sa = prA[posn], sb = prB[posn];
        sSlot[0][t] = min(max(sa, 0), 2 * B_SZ);
        sSlot[1][t] = min(max(sb, 0), 2 * B_SZ);
        sW[0][t] = pw1[posn]; sW[1][t] = pw2[posn];
        sRow[t] = prow[posn];
    }
    __syncthreads();

    f32x4 acc[4][4];
#pragma unroll
    for (int i = 0; i < 4; ++i)
#pragma unroll
        for (int j = 0; j < 4; ++j) acc[i][j] = (f32x4){0.f, 0.f, 0.f, 0.f};

    const int arow0 = t >> 3;          // this thread's 4 staging rows: arow0 + 32*i
    const int akb = t & 7;

#pragma unroll
    for (int ph = 0; ph < 2; ++ph) {
        const __hip_bfloat16* Bg = pwb + (size_t)(ph ? eb : ea) * D_SZ * D_SZ + (size_t)n0 * D_SZ;
        int aslot[4];
#pragma unroll
        for (int i = 0; i < 4; ++i) aslot[i] = sSlot[ph][arow0 + 32 * i];

        for (int kt = 0; kt < D_SZ; kt += 64) {
            __syncthreads();
#pragma unroll
            for (int i = 0; i < 4; ++i) {
                int row = arow0 + 32 * i;
                *(uint4*)&As[akb][row][0] =
                    *(const uint4*)(xsf + (size_t)aslot[i] * D_SZ + kt + akb * 8);
                *(uint4*)&Bs[akb][row][0] =
                    *(const uint4*)(Bg + (size_t)row * D_SZ + kt + akb * 8);
            }
            __syncthreads();
#pragma unroll
            for (int ks = 0; ks < 2; ++ks) {
                int kb = ks * 4 + lg;
                bf16x8 af[4], bfr[4];
#pragma unroll
                for (int ti = 0; ti < 4; ++ti) af[ti]  = *(const bf16x8*)&As[kb][wm + ti * 16 + l15][0];
#pragma unroll
                for (int tj = 0; tj < 4; ++tj) bfr[tj] = *(const bf16x8*)&Bs[kb][wn + tj * 16 + l15][0];
#pragma unroll
                for (int ti = 0; ti < 4; ++ti)
#pragma unroll
                    for (int tj = 0; tj < 4; ++tj)
                        acc[ti][tj] = __builtin_amdgcn_mfma_f32_16x16x32_bf16(
                            af[ti], bfr[tj], acc[ti][tj], 0, 0, 0);
            }
        }
    }

    float pbva[4], pbvb[4];
#pragma unroll
    for (int tj = 0; tj < 4; ++tj) {
        int nc = n0 + wn + tj * 16 + l15;
        pbva[tj] = pb[(size_t)ea * D_SZ + nc];
        pbvb[tj] = pb[(size_t)eb * D_SZ + nc];
    }

#pragma unroll
    for (int ti = 0; ti < 4; ++ti) {
#pragma unroll
        for (int r = 0; r < 4; ++r) {
            int m = wm + ti * 16 + lg * 4 + r;
            if (m0 + m < M) {
                float w1 = sW[0][m], w2 = sW[1][m];
                float* orow = out + (size_t)sRow[m] * D_SZ + n0 + wn + l15;
#pragma unroll
                for (int tj = 0; tj < 4; ++tj)
                    orow[tj * 16] = acc[ti][tj][r] + w1 * pbva[tj] + w2 * pbvb[tj];
            }
        }
    }
}

// ================= host launcher =================
extern "C" void kernel_launch(void* const* d_in, const int* in_sizes, int n_in,
                              void* d_out, int out_size, void* d_ws, size_t ws_size,
                              hipStream_t stream)
{
    const float* x   = (const float*)d_in[0];
    const float* gw1 = (const float*)d_in[1];
    const float* gb1 = (const float*)d_in[2];
    const float* gw2 = (const float*)d_in[3];
    const float* gb2 = (const float*)d_in[4];
    const float* pos = (const float*)d_in[5];
    const float* n1g = (const float*)d_in[6];
    const float* ipw = (const float*)d_in[7];
    const float* ipb = (const float*)d_in[8];
    const float* opw = (const float*)d_in[9];
    const float* opb = (const float*)d_in[10];
    const float* ls1 = (const float*)d_in[11];
    const float* n2g = (const float*)d_in[12];
    const float* fw1 = (const float*)d_in[13];
    const float* fb1 = (const float*)d_in[14];
    const float* fw2 = (const float*)d_in[15];
    const float* fb2 = (const float*)d_in[16];
    const float* ls2 = (const float*)d_in[17];
    const float* pw  = (const float*)d_in[18];
    const float* pb  = (const float*)d_in[19];

    float* out = (float*)d_out;

    char* ws = (char*)d_ws;
    int*   cnt      = (int*)(ws + 0);
    int*   pcnt     = (int*)(ws + 16);
    int*   offA     = (int*)(ws + 80);
    int*   poff     = (int*)(ws + 112);
    int*   topi     = (int*)(ws + WS_TOPI);
    float* topw     = (float*)(ws + WS_TOPW);
    int*   idx_list = (int*)(ws + WS_IDX);
    float* wgt_list = (float*)(ws + WS_WGT);
    int*   er0      = (int*)(ws + WS_ER0);
    int*   er1      = (int*)(ws + WS_ER1);
    int*   prk      = (int*)(ws + WS_PRK);
    int*   bbe      = (int*)(ws + WS_BBE);
    int*   bbp      = (int*)(ws + WS_BBP);
    int*   prA      = (int*)(ws + WS_PRA);
    int*   prB      = (int*)(ws + WS_PRB);
    float* pw1      = (float*)(ws + WS_PW1);
    float* pw2      = (float*)(ws + WS_PW2);
    int*   prow     = (int*)(ws + WS_PRW);
    __hip_bfloat16* xsf  = (__hip_bfloat16*)(ws + WS_XSF);
    __hip_bfloat16* pwb  = (__hip_bfloat16*)(ws + WS_PWB);
    __hip_bfloat16* ipwb = (__hip_bfloat16*)(ws + WS_IPWB);
    __hip_bfloat16* opwb = (__hip_bfloat16*)(ws + WS_OPWB);
    __hip_bfloat16* fw1b = (__hip_bfloat16*)(ws + WS_FW1B);
    __hip_bfloat16* fw2b = (__hip_bfloat16*)(ws + WS_FW2B);

    // zero counters + aux/load slots only (main out region is fully overwritten)
    hipMemsetAsync(d_ws, 0, 256, stream);
    hipMemsetAsync(out + (size_t)B_SZ * D_SZ, 0, 5 * sizeof(float), stream);

    float* load_out = out + (size_t)B_SZ * D_SZ + 1;

    convert_pw<<<NE * D_SZ * D_SZ / (256 * 8), 256, 0, stream>>>(pw, pwb);
    convert_small<<<(N_IPW + N_OPW + N_FW1 + N_FW2) / (256 * 8), 256, 0, stream>>>(
        ipw, opw, fw1, fw2, ls1, ls2, ipwb, opwb, fw1b, fw2b);
    gate_kernel<<<B_SZ, 64, 0, stream>>>(x, gw1, gb1, gw2, gb2, topi, topw);
    count_kernel<<<B_SZ / 256, 256, 0, stream>>>(topi, cnt, pcnt, er0, er1, prk, bbe, bbp);
    offsets_kernel<<<1, 64, 0, stream>>>(cnt, pcnt, offA, poff, load_out);
    fill_kernel<<<B_SZ / 256, 256, 0, stream>>>(topi, topw, offA, poff, er0, er1, prk,
                                                bbe, bbp, idx_list, wgt_list,
                                                prA, prB, pw1, pw2, prow);
    expert_inner<<<(2 * B_SZ) / 4, 256, 0, stream>>>(x, pos, n1g, ipwb, ipb, opwb, opb, ls1,
                                                     n2g, fw1b, fb1, fw2b, fb2, ls2,
                                                     offA, idx_list, wgt_list, xsf);
    proj_pair<<<dim3(96, D_SZ / 128), 256, 0, stream>>>(
        xsf, pwb, pb, poff, prA, prB, pw1, pw2, prow, out);
}